// Round 9
// baseline (106.203 us; speedup 1.0000x reference)
//
#include <hip/hip_runtime.h>
#include <hip/hip_fp16.h>
#include <stdint.h>

// ---------------------------------------------------------------------------
// CIN block: 3 layers of out[b,k,d] = relu(sum_ij h[b,i,d] feat[b,j,d] W[k,i,j] + b[k])
// GEMM view: m=(b,d), Out[k,m] = sum_i W[k,i,:] @ (diag(h[:,i]) F)[:,m]
// R8 = R7 with cvt_pkrtz type fix. 32x32x16 MFMA (half the VALU per FLOP).
// Grid 256 = 32 mg x 8 kg (bx%8=kg -> per-XCD W slice is L2-resident).
// Block: 32 k-cols x 512 m; 16 waves, wave = 32k x 32m, full K.
// W quarter-ring: 2 x 64KB LDS ping-pong, 32 i-slices (2KB) per quarter,
// staged via global_load_lds at quarter start; ONE __syncthreads per 32 steps.
// h = packed f16 pairs, prefetched to VGPRs one quarter ahead (4x dwordx4).
// Per wave-step: 2 ds_read_b128 + 1 v_perm + 8 v_pk_mul_f16 + 2 MFMA.
// C: col=lane&31=m (one b per wave!), row k=(reg&3)+8*(reg>>2)+4*(lane>>5)
// -> d-reduce = 5-level shfl butterfly; h-panel via packed f16 pairs.
// ---------------------------------------------------------------------------

typedef _Float16 half8_t __attribute__((ext_vector_type(8)));
typedef float f32x4 __attribute__((ext_vector_type(4)));
typedef float f32x16 __attribute__((ext_vector_type(16)));
typedef uint32_t u32x4 __attribute__((ext_vector_type(4)));

union H8 {
  half8_t h;
  uint32_t u[4];
  u32x4 q;
};

#define AS1 __attribute__((address_space(1)))
#define AS3 __attribute__((address_space(3)))

static __device__ __forceinline__ uint32_t pkmul(uint32_t x, uint32_t y) {
  __half2 a = __builtin_bit_cast(__half2, x);
  __half2 b = __builtin_bit_cast(__half2, y);
  __half2 r = __hmul2(a, b);
  return __builtin_bit_cast(uint32_t, r);
}

static __device__ __forceinline__ uint32_t pack2h(float a, float b) {
  __half2 r = __floats2half2_rn(a, b);
  return __builtin_bit_cast(uint32_t, r);
}

// ---- fused prep -------------------------------------------------------------
// blocks [0,512): W0 [k][i][j] f32 -> Wt0 chunks [i][kt][g*16+kr][8 f16]
// blocks [512,2560): W1 ; [2560,4608): W2
// blocks [4608,4672): feat -> F16 [m][32 j] f16 and hP0 [mb][4][32][4] u32 pairs
__global__ void prep_kernel(const float* __restrict__ W0, const float* __restrict__ W1,
                            const float* __restrict__ W2, const float* __restrict__ feat,
                            uint16_t* __restrict__ Wt0, uint16_t* __restrict__ Wt1,
                            uint16_t* __restrict__ Wt2,
                            uint16_t* __restrict__ F16, uint32_t* __restrict__ hP0) {
  int blk = blockIdx.x;
  if (blk < 4608) {
    const float* W; uint16_t* Wt; int FLsh, base;
    if (blk < 512)       { W = W0; Wt = Wt0; FLsh = 5; base = 0; }
    else if (blk < 2560) { W = W1; Wt = Wt1; FLsh = 7; base = 512; }
    else                 { W = W2; Wt = Wt2; FLsh = 7; base = 2560; }
    int idx2 = (blk - base) * 256 + threadIdx.x;
    float2 xy = *(const float2*)(W + (size_t)idx2 * 2);
    int j2 = idx2 & 15;                       // f16-pair index along j
    int i = (idx2 >> 4) & ((1 << FLsh) - 1);
    int k = idx2 >> (4 + FLsh);
    __half2 h2 = __floats2half2_rn(xy.x, xy.y);
    int g = j2 >> 2, kr = k & 15, kt = k >> 4;
    uint32_t* wt32 = (uint32_t*)Wt;
    wt32[(((size_t)i * 16 + kt) * 64 + g * 16 + kr) * 4 + (j2 & 3)] = *(uint32_t*)&h2;
  } else {
    int m = (blk - 4608) * 256 + threadIdx.x;  // 0..16383
    int b = m >> 5, d = m & 31;
    const float* fb = feat + (size_t)b * 1024 + d;
    uint16_t hs[32];
#pragma unroll
    for (int j = 0; j < 32; ++j)
      hs[j] = __half_as_ushort(__float2half(fb[j * 32]));
    // hP0 [mb][g4][32 m][4 iw]: pair jp -> (hs[2jp], hs[2jp+1])
    int mb = m >> 5, ml = m & 31;
#pragma unroll
    for (int jp = 0; jp < 16; ++jp) {
      uint32_t pr = (uint32_t)hs[2 * jp] | ((uint32_t)hs[2 * jp + 1] << 16);
      hP0[((size_t)(mb * 4 + (jp >> 2)) * 32 + ml) * 4 + (jp & 3)] = pr;
    }
#pragma unroll
    for (int c = 0; c < 4; ++c) {
      u32x4 q;
      q[0] = (uint32_t)hs[c * 8 + 0] | ((uint32_t)hs[c * 8 + 1] << 16);
      q[1] = (uint32_t)hs[c * 8 + 2] | ((uint32_t)hs[c * 8 + 3] << 16);
      q[2] = (uint32_t)hs[c * 8 + 4] | ((uint32_t)hs[c * 8 + 5] << 16);
      q[3] = (uint32_t)hs[c * 8 + 6] | ((uint32_t)hs[c * 8 + 7] << 16);
      *(u32x4*)(F16 + (size_t)m * 32 + c * 8) = q;
    }
  }
}

// ---- fused CIN layer GEMM ---------------------------------------------------
// grid 256: bx = mg*8 + kg. Block 1024 thr (16 waves); wave w: mb = mg*16+w,
// tile 32k (kg) x 32m (one b), inner FL x 32 j. 32x32x16 MFMA, acc 16 f32.
template <int FL>
__global__ __launch_bounds__(1024, 4) void gemm_cin(
    const uint32_t* __restrict__ hP,    // [mb][FL/8][32][4] u32 f16-pairs
    const uint16_t* __restrict__ wt,    // [FL][16 kt][64][8] f16 chunks
    const uint16_t* __restrict__ f16m,  // [16384][32] f16
    const float* __restrict__ bias,     // [256]
    uint32_t* __restrict__ houtP,       // [mb][16][32][4] pairs (FL_next=128)
    float* __restrict__ outp,           // [512][512] f32
    int obase, int klo) {
  __shared__ __align__(16) char smem[131072];  // 2 x 64KB W quarter buffers
  const int tid = threadIdx.x;
  const int lane = tid & 63, w = tid >> 6;
  const int l31 = lane & 31, l5 = lane >> 5;
  const int bx = blockIdx.x;
  const int kg = bx & 7, mg = bx >> 3;
  const int mb = mg * 16 + w;  // = b; m = mb*32 + l31, d = l31

  // --- resident F fragments: ff[jh] = F[m, jh*16 + l5*8 + e] ---
  const uint16_t* fbase = f16m + (size_t)(mb * 32 + l31) * 32 + l5 * 8;
  H8 ff0, ff1;
  ff0.q = *(const u32x4*)(fbase);
  ff1.q = *(const u32x4*)(fbase + 16);

  // --- h pair base: [mb][g4][32][4] ---
  const uint32_t* hbase = hP + (size_t)mb * (FL / 8) * 128 + l31 * 4;
  u32x4 hqA[4], hqB[4];

  // --- W source: chunk (i*16 + kg*2 + half) ---
  const char* wsrc = (const char*)wt + kg * 2048;

#define CIN_STAGE(QN, BUFOFS)                                                     \
  _Pragma("unroll") for (int c_ = 0; c_ < 4; ++c_) {                              \
    int u_ = w * 4 + c_;                                                          \
    __builtin_amdgcn_global_load_lds(                                             \
        (const AS1 uint32_t*)(wsrc + (size_t)((QN) * 32 + (u_ >> 1)) * 16384 +    \
                              (u_ & 1) * 1024 + lane * 16),                       \
        (AS3 uint32_t*)(smem + (BUFOFS) + u_ * 1024 + lane * 16), 16, 0, 0);      \
  }

#define CIN_HLOAD(QN, HQ)                                                         \
  _Pragma("unroll") for (int c_ = 0; c_ < 4; ++c_)                                \
      HQ[c_] = *(const u32x4*)(hbase + ((QN) * 4 + c_) * 128);

  CIN_STAGE(0, 0)
  CIN_HLOAD(0, hqA)

  f32x16 acc = {};

  // read base: kt2*1024 + l5*256 + kr*16 (+ jh*512 + s*2048 as immediates)
  const char* rb = smem + ((l31 >> 4) << 10) + (l5 << 8) + ((lane & 15) << 4);

  __syncthreads();  // quarter-0 W staged (implicit vmcnt(0) drain)

#define CIN_Q(HQ, RBOFS)                                                          \
  {                                                                               \
    const char* rb_ = rb + (RBOFS);                                               \
    _Pragma("unroll") for (int s = 0; s < 32; ++s) {                              \
      uint32_t hp_ = HQ[s >> 3][(s >> 1) & 3];                                    \
      uint32_t e_ =                                                               \
          __builtin_amdgcn_perm(hp_, hp_, (s & 1) ? 0x03020302u : 0x01000100u);   \
      H8 wf0_, wf1_, b0_, b1_;                                                    \
      wf0_.q = *(const u32x4*)(rb_ + s * 2048);                                   \
      wf1_.q = *(const u32x4*)(rb_ + s * 2048 + 512);                             \
      _Pragma("unroll") for (int c_ = 0; c_ < 4; ++c_) {                          \
        b0_.u[c_] = pkmul(ff0.u[c_], e_);                                         \
        b1_.u[c_] = pkmul(ff1.u[c_], e_);                                         \
      }                                                                           \
      __builtin_amdgcn_s_setprio(1);                                              \
      acc = __builtin_amdgcn_mfma_f32_32x32x16_f16(wf0_.h, b0_.h, acc, 0, 0, 0);  \
      acc = __builtin_amdgcn_mfma_f32_32x32x16_f16(wf1_.h, b1_.h, acc, 0, 0, 0);  \
      __builtin_amdgcn_s_setprio(0);                                              \
    }                                                                             \
  }

  if (FL == 32) {
    CIN_Q(hqA, 0)
  } else {
    CIN_STAGE(1, 65536)
    CIN_HLOAD(1, hqB)
    CIN_Q(hqA, 0)
    __syncthreads();
    CIN_STAGE(2, 0)
    CIN_HLOAD(2, hqA)
    CIN_Q(hqB, 65536)
    __syncthreads();
    CIN_STAGE(3, 65536)
    CIN_HLOAD(3, hqB)
    CIN_Q(hqA, 0)
    __syncthreads();
    CIN_Q(hqB, 65536)
  }
#undef CIN_Q
#undef CIN_STAGE
#undef CIN_HLOAD

  // ---- epilogue: bias + relu; C row k = 8a + 4*l5 + t, col m = l31 ----------
  f32x4 bv[4];
#pragma unroll
  for (int a = 0; a < 4; ++a)
    bv[a] = *(const f32x4*)(bias + kg * 32 + a * 8 + l5 * 4);
  float v[16];
#pragma unroll
  for (int a = 0; a < 4; ++a)
#pragma unroll
    for (int t = 0; t < 4; ++t) {
      float x = acc[a * 4 + t] + bv[a][t];
      v[a * 4 + t] = x > 0.f ? x : 0.f;
    }

  // ---- h panel (k<128 -> kg<4): pairs (k even, k odd) -> hP layout ----------
  if (houtP != nullptr && kg < 4) {
#pragma unroll
    for (int a = 0; a < 4; ++a)
#pragma unroll
      for (int c = 0; c < 2; ++c) {
        uint32_t pr = pack2h(v[a * 4 + 2 * c], v[a * 4 + 2 * c + 1]);
        // i2 = kg*16 + 4a + 2*l5 + c -> g4 = kg*4+a, iw = 2*l5+c
        houtP[((size_t)(mb * 16 + kg * 4 + a) * 32 + l31) * 4 + 2 * l5 + c] = pr;
      }
  }

  // ---- d-reduction: butterfly over 32 lanes (one b per wave) ----------------
#pragma unroll
  for (int r = 0; r < 16; ++r) {
    float x = v[r];
    x += __shfl_xor(x, 1);
    x += __shfl_xor(x, 2);
    x += __shfl_xor(x, 4);
    x += __shfl_xor(x, 8);
    x += __shfl_xor(x, 16);
    v[r] = x;
  }
  if (kg * 32 >= klo && (lane == 0 || lane == 32)) {
    float* ob = outp + (size_t)mb * 512 + obase + kg * 32 - klo + l5 * 4;
#pragma unroll
    for (int a = 0; a < 4; ++a)
      *(f32x4*)(ob + a * 8) = (f32x4){v[a * 4], v[a * 4 + 1], v[a * 4 + 2], v[a * 4 + 3]};
  }
}

// ---------------------------------------------------------------------------
extern "C" void kernel_launch(void* const* d_in, const int* in_sizes, int n_in,
                              void* d_out, int out_size, void* d_ws, size_t ws_size,
                              hipStream_t stream) {
  const float* feat = (const float*)d_in[0];
  const float* W0 = (const float*)d_in[1];
  const float* b0 = (const float*)d_in[2];
  const float* W1 = (const float*)d_in[3];
  const float* b1 = (const float*)d_in[4];
  const float* W2 = (const float*)d_in[5];
  const float* b2 = (const float*)d_in[6];
  float* out = (float*)d_out;
  char* ws = (char*)d_ws;

  // workspace layout (bytes)
  uint16_t* Wt0 = (uint16_t*)(ws + 0x000000);  // 512KB
  uint16_t* Wt1 = (uint16_t*)(ws + 0x080000);  // 2MB
  uint16_t* Wt2 = (uint16_t*)(ws + 0x280000);  // 2MB
  uint16_t* F16 = (uint16_t*)(ws + 0x480000);  // 1MB
  uint32_t* hP0 = (uint32_t*)(ws + 0x580000);  // [512][4][32][4]  u32 = 1MB
  uint32_t* hP1 = (uint32_t*)(ws + 0x680000);  // [512][16][32][4] u32 = 4MB
  uint32_t* hP2 = (uint32_t*)(ws + 0xA80000);  // 4MB (end 14.5MB)

  prep_kernel<<<4672, 256, 0, stream>>>(W0, W1, W2, feat, Wt0, Wt1, Wt2, F16, hP0);

  // layers: out cols [0,128)=L0 k>=128, [128,256)=L1 k>=128, [256,512)=L2 all k
  gemm_cin<32><<<256, 1024, 0, stream>>>(hP0, Wt0, F16, b0, hP1, out, 0, 128);
  gemm_cin<128><<<256, 1024, 0, stream>>>(hP1, Wt1, F16, b1, hP2, out, 128, 128);
  gemm_cin<128><<<256, 1024, 0, stream>>>(hP2, Wt2, F16, b2, (uint32_t*)nullptr,
                                          out, 256, 0);
}

// Round 10
// 95.336 us; speedup vs baseline: 1.1140x; 1.1140x over previous
//
#include <hip/hip_runtime.h>
#include <hip/hip_fp16.h>
#include <stdint.h>

// ---------------------------------------------------------------------------
// CIN block: 3 layers of out[b,k,d] = relu(sum_ij h[b,i,d] feat[b,j,d] W[k,i,j] + b[k])
// GEMM view: m=(b,d), Out[k,m] = sum_i W[k,i,:] @ (diag(h[:,i]) F)[:,m]
// R9: 2 blocks/CU x 4 waves, wave = 64m x 32k (W-frag feeds 4 MFMA -> LDS
// traffic halved below MFMA floor). Grid 512 = 64 mgrp x 8 kg (bx&7=kg ->
// per-XCD W slice L2-resident). W ping-pong 2x32KB (16-i chunks) staged one
// chunk ahead via global_load_lds; boundary = vmcnt(0)+s_barrier (all
// outstanding ops are a full chunk old -> near-free). Barriers sync only 4
// waves; co-resident block decorrelates -> pipe role diversity. No setprio.
// h pairs [mb][g8][iw][32m] -> coalesced h-panel writes (kills the 4x write
// amplification seen in R8: WRITE 27.9MB -> ~9MB).
// ---------------------------------------------------------------------------

typedef _Float16 half8_t __attribute__((ext_vector_type(8)));
typedef float f32x4 __attribute__((ext_vector_type(4)));
typedef float f32x16 __attribute__((ext_vector_type(16)));
typedef uint32_t u32x4 __attribute__((ext_vector_type(4)));

union H8 {
  half8_t h;
  uint32_t u[4];
  u32x4 q;
};

#define AS1 __attribute__((address_space(1)))
#define AS3 __attribute__((address_space(3)))

static __device__ __forceinline__ uint32_t pkmul(uint32_t x, uint32_t y) {
  __half2 a = __builtin_bit_cast(__half2, x);
  __half2 b = __builtin_bit_cast(__half2, y);
  __half2 r = __hmul2(a, b);
  return __builtin_bit_cast(uint32_t, r);
}

static __device__ __forceinline__ uint32_t pack2h(float a, float b) {
  __half2 r = __floats2half2_rn(a, b);
  return __builtin_bit_cast(uint32_t, r);
}

// ---- fused prep -------------------------------------------------------------
// blocks [0,512): W0 [k][i][j] f32 -> Wt0 chunks [i][kt][g*16+kr][8 f16]
// blocks [512,2560): W1 ; [2560,4608): W2
// blocks [4608,4672): feat -> F16 [m][32 j] f16 and hP0 [mb][4 g8][4 iw][32 m]
__global__ void prep_kernel(const float* __restrict__ W0, const float* __restrict__ W1,
                            const float* __restrict__ W2, const float* __restrict__ feat,
                            uint16_t* __restrict__ Wt0, uint16_t* __restrict__ Wt1,
                            uint16_t* __restrict__ Wt2,
                            uint16_t* __restrict__ F16, uint32_t* __restrict__ hP0) {
  int blk = blockIdx.x;
  if (blk < 4608) {
    const float* W; uint16_t* Wt; int FLsh, base;
    if (blk < 512)       { W = W0; Wt = Wt0; FLsh = 5; base = 0; }
    else if (blk < 2560) { W = W1; Wt = Wt1; FLsh = 7; base = 512; }
    else                 { W = W2; Wt = Wt2; FLsh = 7; base = 2560; }
    int idx2 = (blk - base) * 256 + threadIdx.x;
    float2 xy = *(const float2*)(W + (size_t)idx2 * 2);
    int j2 = idx2 & 15;                       // f16-pair index along j
    int i = (idx2 >> 4) & ((1 << FLsh) - 1);
    int k = idx2 >> (4 + FLsh);
    __half2 h2 = __floats2half2_rn(xy.x, xy.y);
    int g = j2 >> 2, kr = k & 15, kt = k >> 4;
    uint32_t* wt32 = (uint32_t*)Wt;
    wt32[(((size_t)i * 16 + kt) * 64 + g * 16 + kr) * 4 + (j2 & 3)] = *(uint32_t*)&h2;
  } else {
    int m = (blk - 4608) * 256 + threadIdx.x;  // 0..16383
    int b = m >> 5, d = m & 31;
    const float* fb = feat + (size_t)b * 1024 + d;
    uint16_t hs[32];
#pragma unroll
    for (int j = 0; j < 32; ++j)
      hs[j] = __half_as_ushort(__float2half(fb[j * 32]));
    // hP0 [mb][g8][iw][32 m]: pair jp -> (hs[2jp], hs[2jp+1])
    int mb = m >> 5, ml = m & 31;
#pragma unroll
    for (int jp = 0; jp < 16; ++jp) {
      uint32_t pr = (uint32_t)hs[2 * jp] | ((uint32_t)hs[2 * jp + 1] << 16);
      hP0[((size_t)(mb * 4 + (jp >> 2)) * 4 + (jp & 3)) * 32 + ml] = pr;
    }
#pragma unroll
    for (int c = 0; c < 4; ++c) {
      u32x4 q;
      q[0] = (uint32_t)hs[c * 8 + 0] | ((uint32_t)hs[c * 8 + 1] << 16);
      q[1] = (uint32_t)hs[c * 8 + 2] | ((uint32_t)hs[c * 8 + 3] << 16);
      q[2] = (uint32_t)hs[c * 8 + 4] | ((uint32_t)hs[c * 8 + 5] << 16);
      q[3] = (uint32_t)hs[c * 8 + 6] | ((uint32_t)hs[c * 8 + 7] << 16);
      *(u32x4*)(F16 + (size_t)m * 32 + c * 8) = q;
    }
  }
}

// ---- fused CIN layer GEMM ---------------------------------------------------
// grid 512: bx = mgrp*8 + kg. Block 256 thr (4 waves); wave w covers
// mb0 = mgrp*8 + w*2 and mb0+1 (64 m) x 32 k (kg), full K. 32x32x16 MFMA.
template <int FL>
__global__ __launch_bounds__(256) void gemm_cin(
    const uint32_t* __restrict__ hP,    // [mb][FL/8 g8][4 iw][32 m] u32 pairs
    const uint16_t* __restrict__ wt,    // [FL][16 kt][64][8] f16 chunks
    const uint16_t* __restrict__ f16m,  // [16384][32] f16
    const float* __restrict__ bias,     // [256]
    uint32_t* __restrict__ houtP,       // [mb][16 g8][4 iw][32 m], or null
    float* __restrict__ outp,           // [512][512] f32
    int obase, int klo) {
  constexpr int NCH = FL / 16;
  __shared__ __align__(16) char smem[65536];  // 2 x 32KB W chunk ping-pong
  const int tid = threadIdx.x;
  const int lane = tid & 63, w = tid >> 6;
  const int l31 = lane & 31, l5 = lane >> 5;
  const int kg = blockIdx.x & 7, mgrp = blockIdx.x >> 3;
  const int mb0 = mgrp * 8 + w * 2;

  // --- W staging addressing: chunk Q = 16 i-slices x 2KB (kt pair kg*2) ---
  const char* wsrc = (const char*)wt + kg * 2048 + (size_t)(tid >> 7) * 16384 +
                     (tid & 127) * 16;
  char* sdst = smem + tid * 16;

#define STAGE(Q)                                                              \
  { _Pragma("unroll") for (int c_ = 0; c_ < 8; ++c_)                          \
      __builtin_amdgcn_global_load_lds(                                       \
          (const AS1 uint32_t*)(wsrc + (size_t)((Q) * 16 + c_ * 2) * 16384),  \
          (AS3 uint32_t*)(sdst + ((Q) & 1) * 32768 + c_ * 4096), 16, 0, 0); }

  // --- h pair streams for both mb ---
  const uint32_t* hbA = hP + (size_t)mb0 * (FL / 8) * 128 + l31;
  const uint32_t* hbB = hbA + (size_t)(FL / 8) * 128;

#define HLD(HB, Q, G, DST)                                                    \
  { const uint32_t* p_ = (HB) + ((Q) * 2 + (G)) * 128;                        \
    DST[0] = p_[0]; DST[1] = p_[32]; DST[2] = p_[64]; DST[3] = p_[96]; }

  // --- prologue: stage chunks 0,1 + h(0) + ff ---
  STAGE(0)
  if (NCH > 1) STAGE(1)
  u32x4 hA0, hA1, hB0, hB1, nA0, nA1, nB0, nB1;
  HLD(hbA, 0, 0, hA0) HLD(hbA, 0, 1, hA1)
  HLD(hbB, 0, 0, hB0) HLD(hbB, 0, 1, hB1)

  const uint16_t* fb0 = f16m + (size_t)(mb0 * 32 + l31) * 32 + l5 * 8;
  H8 ffA0, ffA1, ffB0, ffB1;
  ffA0.q = *(const u32x4*)(fb0);
  ffA1.q = *(const u32x4*)(fb0 + 16);
  ffB0.q = *(const u32x4*)(fb0 + 1024);
  ffB1.q = *(const u32x4*)(fb0 + 1040);

  f32x16 accA = {}, accB = {};
  const char* rb = smem + ((l31 >> 4) << 10) + (l5 << 8) + ((lane & 15) << 4);

  asm volatile("s_waitcnt vmcnt(0)" ::: "memory");
  asm volatile("s_barrier" ::: "memory");

#define CSTEP(S, HCA, HCB, RBQ)                                                    \
  {                                                                                \
    uint32_t hA_ = HCA[((S) >> 1) & 3], hB_ = HCB[((S) >> 1) & 3];                 \
    uint32_t sel_ = ((S) & 1) ? 0x03020302u : 0x01000100u;                         \
    uint32_t eA_ = __builtin_amdgcn_perm(hA_, hA_, sel_);                          \
    uint32_t eB_ = __builtin_amdgcn_perm(hB_, hB_, sel_);                          \
    H8 wf0_, wf1_, bA0_, bA1_, bB0_, bB1_;                                         \
    wf0_.q = *(const u32x4*)((RBQ) + (S) * 2048);                                  \
    wf1_.q = *(const u32x4*)((RBQ) + (S) * 2048 + 512);                            \
    _Pragma("unroll") for (int c_ = 0; c_ < 4; ++c_) {                             \
      bA0_.u[c_] = pkmul(ffA0.u[c_], eA_);                                         \
      bA1_.u[c_] = pkmul(ffA1.u[c_], eA_);                                         \
      bB0_.u[c_] = pkmul(ffB0.u[c_], eB_);                                         \
      bB1_.u[c_] = pkmul(ffB1.u[c_], eB_);                                         \
    }                                                                              \
    accA = __builtin_amdgcn_mfma_f32_32x32x16_f16(wf0_.h, bA0_.h, accA, 0, 0, 0);  \
    accA = __builtin_amdgcn_mfma_f32_32x32x16_f16(wf1_.h, bA1_.h, accA, 0, 0, 0);  \
    accB = __builtin_amdgcn_mfma_f32_32x32x16_f16(wf0_.h, bB0_.h, accB, 0, 0, 0);  \
    accB = __builtin_amdgcn_mfma_f32_32x32x16_f16(wf1_.h, bB1_.h, accB, 0, 0, 0);  \
  }

#define CHUNK(Q, CA0, CA1, CB0, CB1, NA0_, NA1_, NB0_, NB1_)                  \
  {                                                                           \
    const char* rbq_ = rb + ((Q) & 1) * 32768;                                \
    CSTEP(0, CA0, CB0, rbq_) CSTEP(1, CA0, CB0, rbq_)                         \
    if ((Q) + 1 < NCH) {                                                      \
      HLD(hbA, (Q) + 1, 0, NA0_) HLD(hbA, (Q) + 1, 1, NA1_)                   \
      HLD(hbB, (Q) + 1, 0, NB0_) HLD(hbB, (Q) + 1, 1, NB1_)                   \
    }                                                                         \
    CSTEP(2, CA0, CB0, rbq_) CSTEP(3, CA0, CB0, rbq_)                         \
    CSTEP(4, CA0, CB0, rbq_) CSTEP(5, CA0, CB0, rbq_)                         \
    CSTEP(6, CA0, CB0, rbq_) CSTEP(7, CA0, CB0, rbq_)                         \
    CSTEP(8, CA1, CB1, rbq_) CSTEP(9, CA1, CB1, rbq_)                         \
    CSTEP(10, CA1, CB1, rbq_) CSTEP(11, CA1, CB1, rbq_)                       \
    CSTEP(12, CA1, CB1, rbq_) CSTEP(13, CA1, CB1, rbq_)                       \
    CSTEP(14, CA1, CB1, rbq_) CSTEP(15, CA1, CB1, rbq_)                       \
  }

#define BOUNDARY(QS)                                                          \
  {                                                                           \
    asm volatile("s_waitcnt vmcnt(0)" ::: "memory");                          \
    asm volatile("s_barrier" ::: "memory");                                   \
    if ((QS) < NCH) STAGE(QS)                                                 \
  }

#pragma unroll 1
  for (int qq = 0; qq < NCH; qq += 2) {
    CHUNK(qq, hA0, hA1, hB0, hB1, nA0, nA1, nB0, nB1)
    BOUNDARY(qq + 2)
    CHUNK(qq + 1, nA0, nA1, nB0, nB1, hA0, hA1, hB0, hB1)
    if (qq + 2 < NCH) BOUNDARY(qq + 3)
  }
#undef CHUNK
#undef CSTEP
#undef BOUNDARY
#undef STAGE
#undef HLD

  // ---- epilogue: bias+relu; C row k = 8a + 4*l5 + t, col m = l31 ------------
  f32x4 bv[4];
#pragma unroll
  for (int a = 0; a < 4; ++a)
    bv[a] = *(const f32x4*)(bias + kg * 32 + a * 8 + l5 * 4);

#define EPILOG(ACC, MB)                                                           \
  {                                                                               \
    float v[16];                                                                  \
    _Pragma("unroll") for (int a = 0; a < 4; ++a)                                 \
        _Pragma("unroll") for (int t = 0; t < 4; ++t) {                           \
      float x = ACC[a * 4 + t] + bv[a][t];                                        \
      v[a * 4 + t] = x > 0.f ? x : 0.f;                                           \
    }                                                                             \
    if (houtP != nullptr && kg < 4) {                                             \
      _Pragma("unroll") for (int a = 0; a < 4; ++a)                               \
          _Pragma("unroll") for (int c = 0; c < 2; ++c) {                         \
        uint32_t pr = pack2h(v[a * 4 + 2 * c], v[a * 4 + 2 * c + 1]);             \
        houtP[((size_t)((MB) * 16 + kg * 4 + a) * 4 + 2 * l5 + c) * 32 + l31] =   \
            pr;                                                                   \
      }                                                                           \
    }                                                                             \
    _Pragma("unroll") for (int r = 0; r < 16; ++r) {                              \
      float x = v[r];                                                             \
      x += __shfl_xor(x, 1); x += __shfl_xor(x, 2);                               \
      x += __shfl_xor(x, 4); x += __shfl_xor(x, 8);                               \
      x += __shfl_xor(x, 16);                                                     \
      v[r] = x;                                                                   \
    }                                                                             \
    if (kg * 32 >= klo && (lane == 0 || lane == 32)) {                            \
      float* ob = outp + (size_t)(MB) * 512 + obase + kg * 32 - klo + l5 * 4;     \
      _Pragma("unroll") for (int a = 0; a < 4; ++a)                               \
          *(f32x4*)(ob + a * 8) =                                                 \
              (f32x4){v[a * 4], v[a * 4 + 1], v[a * 4 + 2], v[a * 4 + 3]};        \
    }                                                                             \
  }

  EPILOG(accA, mb0)
  EPILOG(accB, mb0 + 1)
#undef EPILOG
}

// ---------------------------------------------------------------------------
extern "C" void kernel_launch(void* const* d_in, const int* in_sizes, int n_in,
                              void* d_out, int out_size, void* d_ws, size_t ws_size,
                              hipStream_t stream) {
  const float* feat = (const float*)d_in[0];
  const float* W0 = (const float*)d_in[1];
  const float* b0 = (const float*)d_in[2];
  const float* W1 = (const float*)d_in[3];
  const float* b1 = (const float*)d_in[4];
  const float* W2 = (const float*)d_in[5];
  const float* b2 = (const float*)d_in[6];
  float* out = (float*)d_out;
  char* ws = (char*)d_ws;

  // workspace layout (bytes)
  uint16_t* Wt0 = (uint16_t*)(ws + 0x000000);  // 512KB
  uint16_t* Wt1 = (uint16_t*)(ws + 0x080000);  // 2MB
  uint16_t* Wt2 = (uint16_t*)(ws + 0x280000);  // 2MB
  uint16_t* F16 = (uint16_t*)(ws + 0x480000);  // 1MB
  uint32_t* hP0 = (uint32_t*)(ws + 0x580000);  // [512][4][4][32]  u32 = 1MB
  uint32_t* hP1 = (uint32_t*)(ws + 0x680000);  // [512][16][4][32] u32 = 4MB
  uint32_t* hP2 = (uint32_t*)(ws + 0xA80000);  // 4MB (end 14.5MB)

  prep_kernel<<<4672, 256, 0, stream>>>(W0, W1, W2, feat, Wt0, Wt1, Wt2, F16, hP0);

  // layers: out cols [0,128)=L0 k>=128, [128,256)=L1 k>=128, [256,512)=L2 all k
  gemm_cin<32><<<512, 256, 0, stream>>>(hP0, Wt0, F16, b0, hP1, out, 0, 128);
  gemm_cin<128><<<512, 256, 0, stream>>>(hP1, Wt1, F16, b1, hP2, out, 128, 128);
  gemm_cin<128><<<512, 256, 0, stream>>>(hP2, Wt2, F16, b2, (uint32_t*)nullptr,
                                         out, 256, 0);
}